// Round 1
// baseline (400.274 us; speedup 1.0000x reference)
//
#include <hip/hip_runtime.h>

// Sizes (static per the reference)
#define BB 4
#define PP 8
#define SS 2048
#define DD 1024
#define HH 16
#define DEPTH 64
#define WINDOW 64
#define NTOK (BB*PP)        // 32 tokens (b,p)
#define KV_ELEMS (NTOK*SS*DD)   // 67,108,864

// workspace layout (floats): q[32*1024] | k[32*1024] | v[32*1024] | z[32*1024]
#define WS_Q 0
#define WS_K 32768
#define WS_V 65536
#define WS_Z 98304

// ---------------- kernel 1: q/k/v projections (GEMV, 32 tokens) -------------
__global__ void proj_qkv(const float* __restrict__ x,
                         const float* __restrict__ Wq, const float* __restrict__ bq,
                         const float* __restrict__ Wk, const float* __restrict__ bk,
                         const float* __restrict__ Wv, const float* __restrict__ bv,
                         float* __restrict__ ws) {
    const int tok = blockIdx.x;        // 0..31
    const int m   = blockIdx.y;        // 0:q 1:k 2:v
    const float* W  = (m == 0) ? Wq : (m == 1) ? Wk : Wv;
    const float* bb = (m == 0) ? bq : (m == 1) ? bk : bv;
    float* out = ws + m * 32768 + tok * DD;

    __shared__ float xs[DD];
    for (int i = threadIdx.x; i < DD; i += 256) xs[i] = x[tok * DD + i];
    __syncthreads();

    const int d0 = threadIdx.x;   // 0..255; covers cols d0, d0+256, d0+512, d0+768
    float a0 = bb[d0], a1 = bb[d0 + 256], a2 = bb[d0 + 512], a3 = bb[d0 + 768];
    for (int i = 0; i < DD; ++i) {
        const float xi = xs[i];
        const float* row = W + (size_t)i * DD + d0;
        a0 = fmaf(xi, row[0],   a0);
        a1 = fmaf(xi, row[256], a1);
        a2 = fmaf(xi, row[512], a2);
        a3 = fmaf(xi, row[768], a3);
    }
    out[d0] = a0; out[d0 + 256] = a1; out[d0 + 512] = a2; out[d0 + 768] = a3;
}

// ---------------- kernel 2: bulk KV copy (float4, grid-stride) ---------------
__global__ void copy_f4(const float4* __restrict__ src, float4* __restrict__ dst,
                        int n4) {
    int i = blockIdx.x * blockDim.x + threadIdx.x;
    const int stride = gridDim.x * blockDim.x;
    for (; i < n4; i += stride) dst[i] = src[i];
}

// ---------------- kernel 3: write projected k/v at row `timestep` ------------
__global__ void write_row(const float* __restrict__ ws,
                          float* __restrict__ outK, float* __restrict__ outV,
                          const int* __restrict__ tptr) {
    const int tok = blockIdx.x;
    const int t = *tptr;
    const float* k = ws + WS_K + tok * DD;
    const float* v = ws + WS_V + tok * DD;
    const size_t base = ((size_t)tok * SS + t) * DD;
    for (int i = threadIdx.x; i < DD; i += 256) {
        outK[base + i] = k[i];
        outV[base + i] = v[i];
    }
}

// ---------------- kernel 4: sliding-window attention (1 wave / (tok,head)) ---
__global__ void attn_win(const float* __restrict__ K, const float* __restrict__ V,
                         float* __restrict__ ws, float* __restrict__ attn_out,
                         const int* __restrict__ tptr) {
    const int bh  = blockIdx.x;    // tok*16 + h
    const int tok = bh >> 4;
    const int h   = bh & 15;
    const int t   = *tptr;
    const int lo  = (t > WINDOW) ? (t - WINDOW) : 0;
    const int count = t - lo + 1;       // <= 65
    const int lane = threadIdx.x;       // 0..63

    const float* q     = ws + WS_Q + tok * DD + h * DEPTH;
    const float* kproj = ws + WS_K + tok * DD + h * DEPTH;
    const float* vproj = ws + WS_V + tok * DD + h * DEPTH;
    const size_t kvbase = (size_t)tok * SS * DD + h * DEPTH;

    __shared__ float sc[80];

    // logits for window positions
    for (int j = lane; j < count; j += 64) {
        const int s = lo + j;
        const float* krow = (s == t) ? kproj : (K + kvbase + (size_t)s * DD);
        float acc = 0.f;
        #pragma unroll
        for (int d = 0; d < DEPTH; ++d) acc = fmaf(q[d], krow[d], acc);
        sc[j] = acc * 0.125f;   // 1/sqrt(64)
    }
    __syncthreads();

    // wave softmax over the window
    float m = -1e30f;
    for (int j = lane; j < count; j += 64) m = fmaxf(m, sc[j]);
    #pragma unroll
    for (int o = 32; o; o >>= 1) m = fmaxf(m, __shfl_xor(m, o));

    float sum = 0.f;
    for (int j = lane; j < count; j += 64) {
        const float e = expf(sc[j] - m);
        sc[j] = e;
        sum += e;
    }
    #pragma unroll
    for (int o = 32; o; o >>= 1) sum += __shfl_xor(sum, o);
    const float inv = 1.f / sum;
    __syncthreads();

    // write full attn row (zeros outside window)
    const size_t arow = (size_t)bh * SS;
    for (int s = lane; s < SS; s += 64) {
        const float val = (s >= lo && s < lo + count) ? sc[s - lo] * inv : 0.f;
        attn_out[arow + s] = val;
    }

    // z_h[lane] = sum_s p[s] * V[s][lane]
    float acc = 0.f;
    for (int j = 0; j < count; ++j) {
        const int s = lo + j;
        const float p = sc[j] * inv;
        const float* vrow = (s == t) ? vproj : (V + kvbase + (size_t)s * DD);
        acc = fmaf(p, vrow[lane], acc);
    }
    ws[WS_Z + tok * DD + h * DEPTH + lane] = acc;
}

// ---------------- kernel 5: output projection z @ Wo + bo --------------------
__global__ void proj_out(const float* __restrict__ ws,
                         const float* __restrict__ Wo, const float* __restrict__ bo,
                         float* __restrict__ out) {
    const int tok = blockIdx.x;
    __shared__ float xs[DD];
    const float* z = ws + WS_Z + tok * DD;
    for (int i = threadIdx.x; i < DD; i += 256) xs[i] = z[i];
    __syncthreads();

    const int d0 = threadIdx.x;
    float a0 = bo[d0], a1 = bo[d0 + 256], a2 = bo[d0 + 512], a3 = bo[d0 + 768];
    for (int i = 0; i < DD; ++i) {
        const float xi = xs[i];
        const float* row = Wo + (size_t)i * DD + d0;
        a0 = fmaf(xi, row[0],   a0);
        a1 = fmaf(xi, row[256], a1);
        a2 = fmaf(xi, row[512], a2);
        a3 = fmaf(xi, row[768], a3);
    }
    out[tok * DD + d0]       = a0;
    out[tok * DD + d0 + 256] = a1;
    out[tok * DD + d0 + 512] = a2;
    out[tok * DD + d0 + 768] = a3;
}

extern "C" void kernel_launch(void* const* d_in, const int* in_sizes, int n_in,
                              void* d_out, int out_size, void* d_ws, size_t ws_size,
                              hipStream_t stream) {
    const float* x  = (const float*)d_in[0];
    const float* K  = (const float*)d_in[1];
    const float* V  = (const float*)d_in[2];
    const float* Wq = (const float*)d_in[3];
    const float* bq = (const float*)d_in[4];
    const float* Wk = (const float*)d_in[5];
    const float* bk = (const float*)d_in[6];
    const float* Wv = (const float*)d_in[7];
    const float* bv = (const float*)d_in[8];
    const float* Wo = (const float*)d_in[9];
    const float* bo = (const float*)d_in[10];
    const int* tptr = (const int*)d_in[11];

    float* out  = (float*)d_out;
    float* outZ = out;                        // (B,P,1,D)      32768
    float* outK = out + 32768;                // (B,P,S,D)      67108864
    float* outV = outK + KV_ELEMS;            // (B,P,S,D)      67108864
    float* outA = outV + KV_ELEMS;            // (B,P,H,1,S)    1048576
    float* ws   = (float*)d_ws;

    // 1. projections
    proj_qkv<<<dim3(NTOK, 3), 256, 0, stream>>>(x, Wq, bq, Wk, bk, Wv, bv, ws);

    // 2. bulk KV passthrough (the memory-bound floor)
    copy_f4<<<4096, 256, 0, stream>>>((const float4*)K, (float4*)outK, KV_ELEMS / 4);
    copy_f4<<<4096, 256, 0, stream>>>((const float4*)V, (float4*)outV, KV_ELEMS / 4);

    // 3. insert updated row at timestep
    write_row<<<NTOK, 256, 0, stream>>>(ws, outK, outV, tptr);

    // 4. sliding-window attention + attn-map write + z
    attn_win<<<NTOK * HH, 64, 0, stream>>>(K, V, ws, outA, tptr);

    // 5. output projection
    proj_out<<<NTOK, 256, 0, stream>>>(ws, Wo, bo, outZ);
}

// Round 2
// 301.873 us; speedup vs baseline: 1.3260x; 1.3260x over previous
//
#include <hip/hip_runtime.h>

#define SS 2048
#define DD 1024
#define HH 16
#define DEPTH 64
#define WINDOW 64
#define NTOK 32                    // B*P
#define KV_ELEMS (NTOK*SS*DD)      // 67,108,864
#define N4 (KV_ELEMS/4)            // 16,777,216 float4s per tensor

typedef float f4 __attribute__((ext_vector_type(4)));

// One kernel does everything.
// Blocks [0,32): full per-token pipeline (proj -> row-t write -> attn -> out proj)
// Blocks [32, ...): bulk KV copy (nontemporal float4), skipping row t
__global__ __launch_bounds__(1024)
void mha_fused(const float* __restrict__ x,
               const float* __restrict__ K, const float* __restrict__ V,
               const float* __restrict__ Wq, const float* __restrict__ bq,
               const float* __restrict__ Wk, const float* __restrict__ bk,
               const float* __restrict__ Wv, const float* __restrict__ bv,
               const float* __restrict__ Wo, const float* __restrict__ bo,
               const int* __restrict__ tptr,
               float* __restrict__ outZ, float* __restrict__ outK,
               float* __restrict__ outV, float* __restrict__ outA) {
    const int t = *tptr;

    if (blockIdx.x >= NTOK) {
        // ---------------- bulk KV copy, skip row t ----------------
        const f4* __restrict__ K4 = (const f4*)K;
        const f4* __restrict__ V4 = (const f4*)V;
        f4* __restrict__ oK4 = (f4*)outK;
        f4* __restrict__ oV4 = (f4*)outV;
        const int stride = (gridDim.x - NTOK) * 1024;
        int i = (blockIdx.x - NTOK) * 1024 + threadIdx.x;
        for (; i < 2 * N4; i += stride) {
            // float4 index -> seq row: elem = i*4; s = (elem>>10)&2047 = (i>>8)&2047
            if (((i >> 8) & 2047) == t) continue;   // token blocks own row t
            if (i < N4) {
                f4 val = __builtin_nontemporal_load(K4 + i);
                __builtin_nontemporal_store(val, oK4 + i);
            } else {
                const int j = i - N4;               // N4 = 2^24: low bits unchanged
                f4 val = __builtin_nontemporal_load(V4 + j);
                __builtin_nontemporal_store(val, oV4 + j);
            }
        }
        return;
    }

    // ---------------- per-token pipeline ----------------
    const int tok  = blockIdx.x;
    const int tid  = threadIdx.x;        // 0..1023
    const int wv   = tid >> 6;           // head 0..15
    const int lane = tid & 63;

    __shared__ float xs[DD];
    __shared__ float qs[DD], ks[DD], vs[DD];
    __shared__ float zs[DD];
    __shared__ float sc[HH][WINDOW + 4]; // per-head window scores (<=65)

    xs[tid] = x[(size_t)tok * DD + tid];
    __syncthreads();

    // q/k/v projections: one output column per thread per matrix
    {
        float aq = bq[tid], ak = bk[tid], av = bv[tid];
        #pragma unroll 4
        for (int i = 0; i < DD; ++i) {
            const float xi = xs[i];
            const size_t off = (size_t)i * DD + tid;
            aq = fmaf(xi, Wq[off], aq);
            ak = fmaf(xi, Wk[off], ak);
            av = fmaf(xi, Wv[off], av);
        }
        qs[tid] = aq; ks[tid] = ak; vs[tid] = av;
    }
    __syncthreads();

    // cache update row t (copy blocks skip this row)
    {
        const size_t base = ((size_t)tok * SS + t) * DD;
        outK[base + tid] = ks[tid];
        outV[base + tid] = vs[tid];
    }

    // ---------------- windowed attention: wave `wv` = head ----------------
    const int lo    = (t > WINDOW) ? (t - WINDOW) : 0;
    const int count = t - lo + 1;        // <= 65
    const size_t kvbase = (size_t)tok * SS * DD + wv * DEPTH;

    // logits
    for (int j = lane; j < count; j += 64) {
        const int s = lo + j;
        float acc = 0.f;
        if (s == t) {
            #pragma unroll
            for (int d = 0; d < DEPTH; ++d)
                acc = fmaf(qs[wv * DEPTH + d], ks[wv * DEPTH + d], acc);
        } else {
            const f4* kr = (const f4*)(K + kvbase + (size_t)s * DD);
            #pragma unroll
            for (int d4 = 0; d4 < DEPTH / 4; ++d4) {
                const f4 kk = kr[d4];
                acc = fmaf(qs[wv * DEPTH + d4 * 4 + 0], kk.x, acc);
                acc = fmaf(qs[wv * DEPTH + d4 * 4 + 1], kk.y, acc);
                acc = fmaf(qs[wv * DEPTH + d4 * 4 + 2], kk.z, acc);
                acc = fmaf(qs[wv * DEPTH + d4 * 4 + 3], kk.w, acc);
            }
        }
        sc[wv][j] = acc * 0.125f;        // 1/sqrt(64)
    }

    // wave softmax (intra-wave LDS ops are ordered; no barrier needed)
    float m = -1e30f;
    for (int j = lane; j < count; j += 64) m = fmaxf(m, sc[wv][j]);
    #pragma unroll
    for (int o = 32; o; o >>= 1) m = fmaxf(m, __shfl_xor(m, o));
    float sum = 0.f;
    for (int j = lane; j < count; j += 64) {
        const float e = expf(sc[wv][j] - m);
        sc[wv][j] = e;
        sum += e;
    }
    #pragma unroll
    for (int o = 32; o; o >>= 1) sum += __shfl_xor(sum, o);
    const float inv = 1.f / sum;
    for (int j = lane; j < count; j += 64) sc[wv][j] *= inv;

    // full attn row (zeros outside window)
    {
        const size_t arow = ((size_t)tok * HH + wv) * SS;
        for (int s2 = lane; s2 < SS; s2 += 64) {
            const float val = (s2 >= lo && s2 <= t) ? sc[wv][s2 - lo] : 0.f;
            outA[arow + s2] = val;
        }
    }

    // z_head[lane] = sum_s p[s] * V[s][lane]
    {
        float acc = 0.f;
        for (int j = 0; j < count; ++j) {
            const int s2 = lo + j;
            const float p = sc[wv][j];
            const float vval = (s2 == t) ? vs[wv * DEPTH + lane]
                                         : V[kvbase + (size_t)s2 * DD + lane];
            acc = fmaf(p, vval, acc);
        }
        zs[wv * DEPTH + lane] = acc;
    }
    __syncthreads();

    // output projection: z @ Wo + bo
    {
        float ao = bo[tid];
        #pragma unroll 4
        for (int i = 0; i < DD; ++i)
            ao = fmaf(zs[i], Wo[(size_t)i * DD + tid], ao);
        outZ[(size_t)tok * DD + tid] = ao;
    }
}

extern "C" void kernel_launch(void* const* d_in, const int* in_sizes, int n_in,
                              void* d_out, int out_size, void* d_ws, size_t ws_size,
                              hipStream_t stream) {
    const float* x  = (const float*)d_in[0];
    const float* K  = (const float*)d_in[1];
    const float* V  = (const float*)d_in[2];
    const float* Wq = (const float*)d_in[3];
    const float* bq = (const float*)d_in[4];
    const float* Wk = (const float*)d_in[5];
    const float* bk = (const float*)d_in[6];
    const float* Wv = (const float*)d_in[7];
    const float* bv = (const float*)d_in[8];
    const float* Wo = (const float*)d_in[9];
    const float* bo = (const float*)d_in[10];
    const int* tptr = (const int*)d_in[11];

    float* out  = (float*)d_out;
    float* outZ = out;                 // (B,P,1,D)   32768
    float* outK = out + 32768;         // (B,P,S,D)   67,108,864
    float* outV = outK + KV_ELEMS;     // (B,P,S,D)   67,108,864
    float* outA = outV + KV_ELEMS;     // (B,P,H,1,S) 1,048,576

    // 32 token blocks + 2048 copy blocks, one launch
    mha_fused<<<NTOK + 2048, 1024, 0, stream>>>(
        x, K, V, Wq, bq, Wk, bk, Wv, bv, Wo, bo, tptr,
        outZ, outK, outV, outA);
}

// Round 3
// 258.303 us; speedup vs baseline: 1.5496x; 1.1687x over previous
//
#include <hip/hip_runtime.h>

#define SS 2048
#define DD 1024
#define HH 16
#define DEPTH 64
#define WINDOW 64
#define NTOK 32
#define KV_ELEMS (NTOK*SS*DD)      // 67,108,864
#define N4 (KV_ELEMS/4)            // 16,777,216 float4 per tensor
#define TOT4 (2*N4)

// ws layout (floats)
#define WS_Q 0
#define WS_K (NTOK*DD)
#define WS_V (2*NTOK*DD)
#define WS_Z (3*NTOK*DD)

typedef float f4 __attribute__((ext_vector_type(4)));

// ---------------- shared copy helper (skips row t; token work owns it) ------
__device__ __forceinline__ void copy_kv(const float* __restrict__ K,
                                        const float* __restrict__ V,
                                        float* __restrict__ outK,
                                        float* __restrict__ outV,
                                        int t, int start, int end,
                                        int cbid, int ncblk) {
    const f4* __restrict__ K4 = (const f4*)K;
    const f4* __restrict__ V4 = (const f4*)V;
    f4* __restrict__ oK4 = (f4*)outK;
    f4* __restrict__ oV4 = (f4*)outV;
    const int stride = ncblk * blockDim.x;
    for (int i = start + cbid * blockDim.x + (int)threadIdx.x; i < end; i += stride) {
        if (i < N4) {
            if (((i >> 8) & (SS - 1)) == t) continue;    // 256 f4 per row
            f4 val = __builtin_nontemporal_load(K4 + i);
            __builtin_nontemporal_store(val, oK4 + i);
        } else {
            const int j = i - N4;
            if (((j >> 8) & (SS - 1)) == t) continue;
            f4 val = __builtin_nontemporal_load(V4 + j);
            __builtin_nontemporal_store(val, oV4 + j);
        }
    }
}

// ---------------- kernel 1: column-parallel QKV proj + copy (K tensor) ------
#define NPROJ 48     // 3 matrices x 16 col-chunks of 64
#define K1COPY 1600

__global__ __launch_bounds__(512)
void k1_proj_copy(const float* __restrict__ x,
                  const float* __restrict__ K, const float* __restrict__ V,
                  const float* __restrict__ Wq, const float* __restrict__ bq,
                  const float* __restrict__ Wk, const float* __restrict__ bk,
                  const float* __restrict__ Wv, const float* __restrict__ bv,
                  const int* __restrict__ tptr,
                  float* __restrict__ ws,
                  float* __restrict__ outK, float* __restrict__ outV,
                  int c0, int c1) {
    const int t = *tptr;
    if (blockIdx.x >= NPROJ) {
        copy_kv(K, V, outK, outV, t, c0, c1, blockIdx.x - NPROJ, gridDim.x - NPROJ);
        return;
    }
    __shared__ __align__(16) float xs[NTOK][128];
    const int m     = blockIdx.x >> 4;       // 0:q 1:k 2:v
    const int chunk = blockIdx.x & 15;       // 64-col chunk
    const float* __restrict__ W  = (m == 0) ? Wq : (m == 1) ? Wk : Wv;
    const float* __restrict__ bb = (m == 0) ? bq : (m == 1) ? bk : bv;
    const int lane = threadIdx.x & 63;
    const int tg   = threadIdx.x >> 6;       // 0..7 -> tokens tg*4..tg*4+3
    const int j    = chunk * 64 + lane;
    const int tok0 = tg * 4;

    float acc0, acc1, acc2, acc3;
    acc0 = acc1 = acc2 = acc3 = bb[j];

    for (int c = 0; c < 8; ++c) {            // 8 row chunks of 128
        __syncthreads();
        for (int r = threadIdx.x; r < NTOK * 32; r += 512) {
            const int tok = r >> 5, q4 = r & 31;
            ((f4*)xs[tok])[q4] = ((const f4*)(x + (size_t)tok * DD + c * 128))[q4];
        }
        __syncthreads();
        const float* Wc = W + (size_t)(c * 128) * DD + j;
        #pragma unroll 2
        for (int il4 = 0; il4 < 32; ++il4) {
            const int il = il4 * 4;
            const float w0 = Wc[(size_t)(il + 0) * DD];
            const float w1 = Wc[(size_t)(il + 1) * DD];
            const float w2 = Wc[(size_t)(il + 2) * DD];
            const float w3 = Wc[(size_t)(il + 3) * DD];
            const f4 x0 = ((const f4*)xs[tok0 + 0])[il4];
            const f4 x1 = ((const f4*)xs[tok0 + 1])[il4];
            const f4 x2 = ((const f4*)xs[tok0 + 2])[il4];
            const f4 x3 = ((const f4*)xs[tok0 + 3])[il4];
            acc0 = fmaf(w3, x0.w, fmaf(w2, x0.z, fmaf(w1, x0.y, fmaf(w0, x0.x, acc0))));
            acc1 = fmaf(w3, x1.w, fmaf(w2, x1.z, fmaf(w1, x1.y, fmaf(w0, x1.x, acc1))));
            acc2 = fmaf(w3, x2.w, fmaf(w2, x2.z, fmaf(w1, x2.y, fmaf(w0, x2.x, acc2))));
            acc3 = fmaf(w3, x3.w, fmaf(w2, x3.z, fmaf(w1, x3.y, fmaf(w0, x3.x, acc3))));
        }
    }
    float* dst = ws + m * (NTOK * DD);
    dst[(size_t)(tok0 + 0) * DD + j] = acc0;
    dst[(size_t)(tok0 + 1) * DD + j] = acc1;
    dst[(size_t)(tok0 + 2) * DD + j] = acc2;
    dst[(size_t)(tok0 + 3) * DD + j] = acc3;
    if (m == 1) {
        outK[((size_t)(tok0 + 0) * SS + t) * DD + j] = acc0;
        outK[((size_t)(tok0 + 1) * SS + t) * DD + j] = acc1;
        outK[((size_t)(tok0 + 2) * SS + t) * DD + j] = acc2;
        outK[((size_t)(tok0 + 3) * SS + t) * DD + j] = acc3;
    } else if (m == 2) {
        outV[((size_t)(tok0 + 0) * SS + t) * DD + j] = acc0;
        outV[((size_t)(tok0 + 1) * SS + t) * DD + j] = acc1;
        outV[((size_t)(tok0 + 2) * SS + t) * DD + j] = acc2;
        outV[((size_t)(tok0 + 3) * SS + t) * DD + j] = acc3;
    }
}

// ---------------- kernel 2: windowed attention + copy (part of V) -----------
#define NATTN 128    // 4 heads per block, 512 heads
#define K2COPY 1024

__global__ __launch_bounds__(256)
void k2_attn_copy(const float* __restrict__ K, const float* __restrict__ V,
                  const int* __restrict__ tptr,
                  float* __restrict__ ws, float* __restrict__ outA,
                  float* __restrict__ outK, float* __restrict__ outV,
                  int c0, int c1) {
    const int t = *tptr;
    if (blockIdx.x >= NATTN) {
        copy_kv(K, V, outK, outV, t, c0, c1, blockIdx.x - NATTN, gridDim.x - NATTN);
        return;
    }
    const int wv   = threadIdx.x >> 6;
    const int lane = threadIdx.x & 63;
    const int tok  = blockIdx.x >> 2;
    const int h0   = (blockIdx.x & 3) * 4;   // this block: heads h0..h0+3
    const int h    = h0 + wv;

    __shared__ float qh[4][DEPTH], kh[4][DEPTH], vh[4][DEPTH];
    __shared__ float sc[4][WINDOW + 8];

    {   // stage 4 heads' q/k/v slices (256 contiguous floats each)
        const int base = tok * DD + h0 * DEPTH;
        ((float*)qh)[threadIdx.x] = ws[WS_Q + base + threadIdx.x];
        ((float*)kh)[threadIdx.x] = ws[WS_K + base + threadIdx.x];
        ((float*)vh)[threadIdx.x] = ws[WS_V + base + threadIdx.x];
    }
    __syncthreads();

    const int lo    = (t > WINDOW) ? (t - WINDOW) : 0;
    const int count = t - lo + 1;            // <= 65
    const size_t kvbase = (size_t)tok * SS * DD + h * DEPTH;

    for (int jj = lane; jj < count; jj += 64) {
        const int s = lo + jj;
        float acc = 0.f;
        if (s == t) {
            #pragma unroll
            for (int d = 0; d < DEPTH; ++d) acc = fmaf(qh[wv][d], kh[wv][d], acc);
        } else {
            const f4* kr = (const f4*)(K + kvbase + (size_t)s * DD);
            #pragma unroll
            for (int d4 = 0; d4 < DEPTH / 4; ++d4) {
                const f4 kk = kr[d4];
                acc = fmaf(qh[wv][d4 * 4 + 0], kk.x, acc);
                acc = fmaf(qh[wv][d4 * 4 + 1], kk.y, acc);
                acc = fmaf(qh[wv][d4 * 4 + 2], kk.z, acc);
                acc = fmaf(qh[wv][d4 * 4 + 3], kk.w, acc);
            }
        }
        sc[wv][jj] = acc * 0.125f;           // 1/sqrt(64)
    }

    // wave softmax (intra-wave LDS ordering)
    float mx = -1e30f;
    for (int jj = lane; jj < count; jj += 64) mx = fmaxf(mx, sc[wv][jj]);
    #pragma unroll
    for (int o = 32; o; o >>= 1) mx = fmaxf(mx, __shfl_xor(mx, o));
    float sum = 0.f;
    for (int jj = lane; jj < count; jj += 64) {
        const float e = expf(sc[wv][jj] - mx);
        sc[wv][jj] = e;
        sum += e;
    }
    #pragma unroll
    for (int o = 32; o; o >>= 1) sum += __shfl_xor(sum, o);
    const float inv = 1.f / sum;
    for (int jj = lane; jj < count; jj += 64) sc[wv][jj] *= inv;

    // full attn row (zeros outside window), vectorized
    {
        f4* oa = (f4*)(outA + ((size_t)tok * HH + h) * SS);
        for (int q4 = lane; q4 < SS / 4; q4 += 64) {
            const int s0 = q4 * 4;
            f4 val;
            val.x = (s0 + 0 >= lo && s0 + 0 <= t) ? sc[wv][s0 + 0 - lo] : 0.f;
            val.y = (s0 + 1 >= lo && s0 + 1 <= t) ? sc[wv][s0 + 1 - lo] : 0.f;
            val.z = (s0 + 2 >= lo && s0 + 2 <= t) ? sc[wv][s0 + 2 - lo] : 0.f;
            val.w = (s0 + 3 >= lo && s0 + 3 <= t) ? sc[wv][s0 + 3 - lo] : 0.f;
            __builtin_nontemporal_store(val, oa + q4);
        }
    }

    // z[h][lane] = sum_s p[s] * V[s][h*64+lane]
    {
        float acc = 0.f;
        #pragma unroll 4
        for (int jj = 0; jj < count - 1; ++jj)
            acc = fmaf(sc[wv][jj], V[kvbase + (size_t)(lo + jj) * DD + lane], acc);
        acc = fmaf(sc[wv][count - 1], vh[wv][lane], acc);
        ws[WS_Z + (size_t)tok * DD + h * DEPTH + lane] = acc;
    }
}

// ---------------- kernel 3: column-parallel out-proj + copy (rest) ----------
#define NOUT 16
#define K3COPY 768

__global__ __launch_bounds__(512)
void k3_out_copy(const float* __restrict__ K, const float* __restrict__ V,
                 const float* __restrict__ Wo, const float* __restrict__ bo,
                 const int* __restrict__ tptr,
                 const float* __restrict__ ws,
                 float* __restrict__ outZ,
                 float* __restrict__ outK, float* __restrict__ outV,
                 int c0, int c1) {
    const int t = *tptr;
    if (blockIdx.x >= NOUT) {
        copy_kv(K, V, outK, outV, t, c0, c1, blockIdx.x - NOUT, gridDim.x - NOUT);
        return;
    }
    __shared__ __align__(16) float zsh[NTOK][128];
    const int chunk = blockIdx.x;
    const int lane = threadIdx.x & 63;
    const int tg   = threadIdx.x >> 6;
    const int j    = chunk * 64 + lane;
    const int tok0 = tg * 4;
    const float* __restrict__ z = ws + WS_Z;

    float acc0, acc1, acc2, acc3;
    acc0 = acc1 = acc2 = acc3 = bo[j];

    for (int c = 0; c < 8; ++c) {
        __syncthreads();
        for (int r = threadIdx.x; r < NTOK * 32; r += 512) {
            const int tok = r >> 5, q4 = r & 31;
            ((f4*)zsh[tok])[q4] = ((const f4*)(z + (size_t)tok * DD + c * 128))[q4];
        }
        __syncthreads();
        const float* Wc = Wo + (size_t)(c * 128) * DD + j;
        #pragma unroll 2
        for (int il4 = 0; il4 < 32; ++il4) {
            const int il = il4 * 4;
            const float w0 = Wc[(size_t)(il + 0) * DD];
            const float w1 = Wc[(size_t)(il + 1) * DD];
            const float w2 = Wc[(size_t)(il + 2) * DD];
            const float w3 = Wc[(size_t)(il + 3) * DD];
            const f4 x0 = ((const f4*)zsh[tok0 + 0])[il4];
            const f4 x1 = ((const f4*)zsh[tok0 + 1])[il4];
            const f4 x2 = ((const f4*)zsh[tok0 + 2])[il4];
            const f4 x3 = ((const f4*)zsh[tok0 + 3])[il4];
            acc0 = fmaf(w3, x0.w, fmaf(w2, x0.z, fmaf(w1, x0.y, fmaf(w0, x0.x, acc0))));
            acc1 = fmaf(w3, x1.w, fmaf(w2, x1.z, fmaf(w1, x1.y, fmaf(w0, x1.x, acc1))));
            acc2 = fmaf(w3, x2.w, fmaf(w2, x2.z, fmaf(w1, x2.y, fmaf(w0, x2.x, acc2))));
            acc3 = fmaf(w3, x3.w, fmaf(w2, x3.z, fmaf(w1, x3.y, fmaf(w0, x3.x, acc3))));
        }
    }
    outZ[(size_t)(tok0 + 0) * DD + j] = acc0;
    outZ[(size_t)(tok0 + 1) * DD + j] = acc1;
    outZ[(size_t)(tok0 + 2) * DD + j] = acc2;
    outZ[(size_t)(tok0 + 3) * DD + j] = acc3;
}

extern "C" void kernel_launch(void* const* d_in, const int* in_sizes, int n_in,
                              void* d_out, int out_size, void* d_ws, size_t ws_size,
                              hipStream_t stream) {
    const float* x  = (const float*)d_in[0];
    const float* K  = (const float*)d_in[1];
    const float* V  = (const float*)d_in[2];
    const float* Wq = (const float*)d_in[3];
    const float* bq = (const float*)d_in[4];
    const float* Wk = (const float*)d_in[5];
    const float* bk = (const float*)d_in[6];
    const float* Wv = (const float*)d_in[7];
    const float* bv = (const float*)d_in[8];
    const float* Wo = (const float*)d_in[9];
    const float* bo = (const float*)d_in[10];
    const int* tptr = (const int*)d_in[11];

    float* out  = (float*)d_out;
    float* outZ = out;                 // (B,P,1,D)   32,768
    float* outK = out + 32768;         // (B,P,S,D)   67,108,864
    float* outV = outK + KV_ELEMS;     // (B,P,S,D)   67,108,864
    float* outA = outV + KV_ELEMS;     // (B,P,H,1,S) 1,048,576
    float* ws   = (float*)d_ws;

    const int C2 = 10485760;           // k2's share of the V copy (f4 units)

    k1_proj_copy<<<NPROJ + K1COPY, 512, 0, stream>>>(
        x, K, V, Wq, bq, Wk, bk, Wv, bv, tptr, ws, outK, outV, 0, N4);
    k2_attn_copy<<<NATTN + K2COPY, 256, 0, stream>>>(
        K, V, tptr, ws, outA, outK, outV, N4, N4 + C2);
    k3_out_copy<<<NOUT + K3COPY, 512, 0, stream>>>(
        K, V, Wo, bo, tptr, ws, outZ, outK, outV, N4 + C2, TOT4);
}